// Round 7
// baseline (1099.049 us; speedup 1.0000x reference)
//
#include <hip/hip_runtime.h>
#include <math.h>

#define DIM    512
#define KCB    8192
#define NROWS  32768

typedef _Float16 f16x8 __attribute__((ext_vector_type(8)));
typedef float    f32x4 __attribute__((ext_vector_type(4)));

// ---- workspace layout (main path) ----
#define OFF_ZH    0ull                    // f16 Z  [32768][512] = 33554432 B
#define OFF_EH    33554432ull             // f16 E*8192 [8192][512] = 8388608 B
#define OFF_EE    41943040ull             // f32 ee [8192]
#define OFF_ZZ    41975808ull             // f32 zz [32768]
#define OFF_CNT   42106880ull             // u32 cnt[32768]
#define OFF_LOSS  42237952ull             // f64 loss accumulator
#define OFF_CAND  42237960ull             // u32 cand[32768][64]
#define WS_NEEDED 50626568ull
#define CAP 64
// screen keeps k if dot16_scaled >= runmax - THR (E scaled by 2^13; folds ee
// and all f16 error into the margin; r3/r5-proven equivalent dot-margin).
#define THR 2.048f

__device__ __forceinline__ void gl_lds16(const void* g, void* l) {
    __builtin_amdgcn_global_load_lds(
        (const __attribute__((address_space(1))) unsigned int*)g,
        (__attribute__((address_space(3))) unsigned int*)l, 16, 0, 0);
}

// ---------------------------------------------------------------------------
// numpy-pairwise sum of squares over 512 floats + fused f16 conversion/store.
// Sum arithmetic chain is bit-identical to the round-1..6 passing version
// (conversions use the same loaded values; they do not perturb the sum).
// ---------------------------------------------------------------------------
__device__ __forceinline__ float pairwise_cvt(const float* __restrict__ p,
                                              _Float16* __restrict__ o, float scale) {
    float blk[4];
#pragma unroll
    for (int b = 0; b < 4; ++b) {
        const float4* a4 = (const float4*)(p + b * 128);
        float4 v0 = a4[0], v1 = a4[1];
        float r[8];
        r[0] = __fmul_rn(v0.x, v0.x); r[1] = __fmul_rn(v0.y, v0.y);
        r[2] = __fmul_rn(v0.z, v0.z); r[3] = __fmul_rn(v0.w, v0.w);
        r[4] = __fmul_rn(v1.x, v1.x); r[5] = __fmul_rn(v1.y, v1.y);
        r[6] = __fmul_rn(v1.z, v1.z); r[7] = __fmul_rn(v1.w, v1.w);
        {
            f16x8 h;
            h[0] = (_Float16)(v0.x * scale); h[1] = (_Float16)(v0.y * scale);
            h[2] = (_Float16)(v0.z * scale); h[3] = (_Float16)(v0.w * scale);
            h[4] = (_Float16)(v1.x * scale); h[5] = (_Float16)(v1.y * scale);
            h[6] = (_Float16)(v1.z * scale); h[7] = (_Float16)(v1.w * scale);
            *(f16x8*)(o + b * 128) = h;
        }
#pragma unroll
        for (int i = 1; i < 16; ++i) {
            v0 = a4[i * 2]; v1 = a4[i * 2 + 1];
            r[0] = __fadd_rn(r[0], __fmul_rn(v0.x, v0.x));
            r[1] = __fadd_rn(r[1], __fmul_rn(v0.y, v0.y));
            r[2] = __fadd_rn(r[2], __fmul_rn(v0.z, v0.z));
            r[3] = __fadd_rn(r[3], __fmul_rn(v0.w, v0.w));
            r[4] = __fadd_rn(r[4], __fmul_rn(v1.x, v1.x));
            r[5] = __fadd_rn(r[5], __fmul_rn(v1.y, v1.y));
            r[6] = __fadd_rn(r[6], __fmul_rn(v1.z, v1.z));
            r[7] = __fadd_rn(r[7], __fmul_rn(v1.w, v1.w));
            f16x8 h;
            h[0] = (_Float16)(v0.x * scale); h[1] = (_Float16)(v0.y * scale);
            h[2] = (_Float16)(v0.z * scale); h[3] = (_Float16)(v0.w * scale);
            h[4] = (_Float16)(v1.x * scale); h[5] = (_Float16)(v1.y * scale);
            h[6] = (_Float16)(v1.z * scale); h[7] = (_Float16)(v1.w * scale);
            *(f16x8*)(o + b * 128 + i * 8) = h;
        }
        blk[b] = __fadd_rn(__fadd_rn(__fadd_rn(r[0], r[1]), __fadd_rn(r[2], r[3])),
                           __fadd_rn(__fadd_rn(r[4], r[5]), __fadd_rn(r[6], r[7])));
    }
    return __fadd_rn(__fadd_rn(blk[0], blk[1]), __fadd_rn(blk[2], blk[3]));
}

// fused prep: zz + Zh + cnt=0 (rows), ee + Eh (codes), lossAcc=0
__global__ __launch_bounds__(256)
void prep_kernel(const float* __restrict__ Z, const float* __restrict__ E,
                 _Float16* __restrict__ Zh, _Float16* __restrict__ Eh,
                 float* __restrict__ zz, float* __restrict__ ee,
                 unsigned int* __restrict__ cnt, double* __restrict__ lossAcc) {
    int id = blockIdx.x * 256 + threadIdx.x;
    if (id == 0) *lossAcc = 0.0;
    if (id < NROWS) {
        zz[id] = pairwise_cvt(Z + (size_t)id * DIM, Zh + (size_t)id * DIM, 1.0f);
        cnt[id] = 0;
    } else {
        int k = id - NROWS;
        ee[k] = pairwise_cvt(E + (size_t)k * DIM, Eh + (size_t)k * DIM, 8192.0f);
    }
}

// ---------------------------------------------------------------------------
// Screen v6: 256 blocks x 512 thr (8 waves, 2 wrow x 4 wcol), 128 rows/block.
// BK=64: 256 steps (32 tiles x 8 ksteps). Ring-3 x 48 KiB slots (A 16 KiB +
// B 32 KiB), DMA-staged 2 steps ahead. PIPELINED FRAGS: step s's MFMA uses
// registers read at step s-1; step s issues reads for s+1 — MFMA never waits
// on LDS. Per step:
//   lgkmcnt(0)  my slot-s reads (issued s-1) landed        [free: ~1 step old]
//   vmcnt(6)    my batch s+1 DMAs retired                  [free: 2-step look]
//   s_barrier   => slot s+1 complete, slot s safe to overwrite
//   STAGE(s+3 -> slot s%3); READ frags(s+1) -> other reg set; 32 MFMA(s).
// Unit layout (16B units, 8/row): pos = k_unit ^ (row&7) — every bank gets
// exactly 8 words per b128 wave-read (balanced) and DMA dests are lane-linear.
// ---------------------------------------------------------------------------
__global__ __launch_bounds__(512, 2)
void screen_kernel(const _Float16* __restrict__ Zh, const _Float16* __restrict__ Eh,
                   unsigned int* __restrict__ cnt, unsigned int* __restrict__ cand) {
    __shared__ __align__(16) char lds[3 * 49152];   // 144 KiB

    const int tid = threadIdx.x;
    const int l = tid & 63;
    const int w = tid >> 6;
    const int wrow = w >> 2, wcol = w & 3;
    const int rowBase = blockIdx.x * 128;
    const int q = l >> 4;

    // stage addressing: unit d -> row d>>3, pos d&7, src slot pos^(row&7).
    // i-increments of 64 units = +8 rows: src +4096 elem, dst +1024 B.
    const int dA = w * 128 + l;
    const int rA = dA >> 3, pA = dA & 7;
    const _Float16* srcA0 = Zh + (size_t)(rowBase + rA) * DIM + (pA ^ (rA & 7)) * 8;
    const int dstA0 = rA * 128 + pA * 16;
    const int dB = w * 256 + l;
    const int cB = dB >> 3, pB = dB & 7;
    const _Float16* srcB0 = Eh + (size_t)cB * DIM + (pB ^ (cB & 7)) * 8;
    const int dstB0 = 16384 + cB * 128 + pB * 16;

    // frag read offsets at m=n=0; +2048 B per m/n (row&7 invariant in m*16)
    const int rowA0 = wrow * 64 + (l & 15);
    const int colB0 = wcol * 64 + (l & 15);
    int offA0[2], offB0[2];
#pragma unroll
    for (int k2 = 0; k2 < 2; ++k2) {
        offA0[k2] = (rowA0 * 8 + ((k2 * 4 + q) ^ (rowA0 & 7))) * 16;
        offB0[k2] = 16384 + (colB0 * 8 + ((k2 * 4 + q) ^ (colB0 & 7))) * 16;
    }

#define STAGE(stp, sbase) do {                                                 \
        const int _t = (stp) >> 3, _k = (stp) & 7;                             \
        const int _ao = _k * 64;                                               \
        const int _bo = _t * 131072 + _k * 64;                                 \
        gl_lds16(srcA0 + _ao,         lds + (sbase) + dstA0);                  \
        gl_lds16(srcA0 + _ao + 4096,  lds + (sbase) + dstA0 + 1024);           \
        gl_lds16(srcB0 + _bo,         lds + (sbase) + dstB0);                  \
        gl_lds16(srcB0 + _bo + 4096,  lds + (sbase) + dstB0 + 1024);           \
        gl_lds16(srcB0 + _bo + 8192,  lds + (sbase) + dstB0 + 2048);           \
        gl_lds16(srcB0 + _bo + 12288, lds + (sbase) + dstB0 + 3072);           \
    } while (0)

#define READF(AF, BF, rbase) do {                                              \
        _Pragma("unroll")                                                      \
        for (int _m = 0; _m < 4; ++_m) {                                       \
            AF[_m][0] = *(const f16x8*)(lds + (rbase) + offA0[0] + _m * 2048); \
            AF[_m][1] = *(const f16x8*)(lds + (rbase) + offA0[1] + _m * 2048); \
        }                                                                      \
        _Pragma("unroll")                                                      \
        for (int _n = 0; _n < 4; ++_n) {                                       \
            BF[_n][0] = *(const f16x8*)(lds + (rbase) + offB0[0] + _n * 2048); \
            BF[_n][1] = *(const f16x8*)(lds + (rbase) + offB0[1] + _n * 2048); \
        }                                                                      \
    } while (0)

#define MFMA32(AF, BF) do {                                                    \
        __builtin_amdgcn_s_setprio(1);                                         \
        _Pragma("unroll")                                                      \
        for (int _k = 0; _k < 2; ++_k)                                         \
        _Pragma("unroll")                                                      \
        for (int _m = 0; _m < 4; ++_m)                                         \
        _Pragma("unroll")                                                      \
        for (int _n = 0; _n < 4; ++_n)                                         \
            acc[_m][_n] = __builtin_amdgcn_mfma_f32_16x16x32_f16(              \
                AF[_m][_k], BF[_n][_k], acc[_m][_n], 0, 0, 0);                 \
        __builtin_amdgcn_s_setprio(0);                                         \
    } while (0)

    STAGE(0, 0); STAGE(1, 49152); STAGE(2, 98304);

    float runmax[16];
#pragma unroll
    for (int t = 0; t < 16; ++t) runmax[t] = -__builtin_inff();

    f16x8 a0[4][2], b0[4][2], a1[4][2], b1[4][2];
    asm volatile("s_waitcnt vmcnt(12)" ::: "memory");   // batch 0 retired
    asm volatile("s_barrier" ::: "memory");
    READF(a0, b0, 0);                                    // frags for step 0

    int stBase = 0, rdBase = 49152;

    for (int tile = 0; tile < 32; ++tile) {
        f32x4 acc[4][4];
#pragma unroll
        for (int m = 0; m < 4; ++m)
#pragma unroll
            for (int n = 0; n < 4; ++n) acc[m][n] = (f32x4){0.f, 0.f, 0.f, 0.f};

#pragma unroll
        for (int ks = 0; ks < 8; ++ks) {
            const int s = tile * 8 + ks;
            asm volatile("s_waitcnt lgkmcnt(0)" ::: "memory");
            if (s >= 254) asm volatile("s_waitcnt vmcnt(0)" ::: "memory");
            else          asm volatile("s_waitcnt vmcnt(6)" ::: "memory");
            asm volatile("s_barrier" ::: "memory");
            if (s <= 252) STAGE(s + 3, stBase);
            if ((ks & 1) == 0) {
                if (s < 255) READF(a1, b1, rdBase);
                MFMA32(a0, b0);
            } else {
                if (s < 255) READF(a0, b0, rdBase);
                MFMA32(a1, b1);
            }
            stBase = rdBase;
            rdBase = (rdBase == 98304) ? 0 : rdBase + 49152;
        }

        // epilogue: screen on raw scaled dot (ee folded into THR) — r6 verbatim
#pragma unroll
        for (int m = 0; m < 4; ++m) {
#pragma unroll
            for (int r = 0; r < 4; ++r) {
                float mx = fmaxf(fmaxf(acc[m][0][r], acc[m][1][r]),
                                 fmaxf(acc[m][2][r], acc[m][3][r]));
#pragma unroll
                for (int off = 1; off < 16; off <<= 1)
                    mx = fmaxf(mx, __shfl_xor(mx, off, 64));
                const int qq = m * 4 + r;
                const float rm = fmaxf(runmax[qq], mx);
                runmax[qq] = rm;
                const float thr = rm - THR;
                const int rowg = rowBase + wrow * 64 + m * 16 + (l >> 4) * 4 + r;
#pragma unroll
                for (int n = 0; n < 4; ++n) {
                    if (acc[m][n][r] >= thr) {
                        unsigned pos = atomicAdd(&cnt[rowg], 1u);
                        if (pos < CAP)
                            cand[(size_t)rowg * CAP + pos] =
                                (unsigned)(tile * 256 + wcol * 64 + n * 16 + (l & 15));
                    }
                }
            }
        }
    }
#undef STAGE
#undef READF
#undef MFMA32
}

// ---------------------------------------------------------------------------
// finish: rescore (exact, bit-identical chain) + gather + loss (r6 verbatim).
// ---------------------------------------------------------------------------
__global__ __launch_bounds__(256)
void finish_kernel(const float* __restrict__ Z, const float* __restrict__ E,
                   const float* __restrict__ zz, const float* __restrict__ ee,
                   const unsigned int* __restrict__ cnt,
                   const unsigned int* __restrict__ cand,
                   float* __restrict__ outZ, float* __restrict__ outIdxF,
                   double* __restrict__ lossAcc) {
    __shared__ double psum[4];
    const int tid = threadIdx.x;
    const int l = tid & 63;
    const int w = tid >> 6;
    double s = 0.0;

    for (int j = 0; j < 8; ++j) {
        const int row = blockIdx.x * 32 + w * 8 + j;
        unsigned c = cnt[row]; if (c > CAP) c = CAP;
        int kk;
        if (c == 1) {
            kk = (int)cand[(size_t)row * CAP];
        } else {
            float d2 = __builtin_inff();
            int kl = 0x7FFFFFFF;
            if (l < (int)c) {
                int k = (int)cand[(size_t)row * CAP + l];
                const float4* zr4 = (const float4*)(Z + (size_t)row * DIM);
                const float4* er4 = (const float4*)(E + (size_t)k * DIM);
                float acc = 0.0f;
#pragma unroll 8
                for (int i = 0; i < DIM / 4; ++i) {
                    float4 z4 = zr4[i], e4 = er4[i];
                    acc = __builtin_fmaf(z4.x, e4.x, acc);
                    acc = __builtin_fmaf(z4.y, e4.y, acc);
                    acc = __builtin_fmaf(z4.z, e4.z, acc);
                    acc = __builtin_fmaf(z4.w, e4.w, acc);
                }
                float t = __builtin_fmaf(-2.0f, acc, zz[row]);
                d2 = __fadd_rn(t, ee[k]);
                kl = k;
            }
#pragma unroll
            for (int off = 32; off > 0; off >>= 1) {
                float od = __shfl_down(d2, off, 64);
                int ok = __shfl_down(kl, off, 64);
                if (od < d2 || (od == d2 && ok < kl)) { d2 = od; kl = ok; }
            }
            kk = __shfl(kl, 0, 64);
        }
        const float* zr = Z + (size_t)row * DIM;
        const float* er = E + (size_t)kk * DIM;
        float* orow = outZ + (size_t)row * DIM;
#pragma unroll
        for (int i = 0; i < 2; ++i) {
            int off = (l + i * 64) * 4;
            float4 z4 = *(const float4*)(zr + off);
            float4 e4 = *(const float4*)(er + off);
            float dx = __fsub_rn(e4.x, z4.x);
            float dy = __fsub_rn(e4.y, z4.y);
            float dz = __fsub_rn(e4.z, z4.z);
            float dw = __fsub_rn(e4.w, z4.w);
            float4 st;
            st.x = __fadd_rn(z4.x, dx);
            st.y = __fadd_rn(z4.y, dy);
            st.z = __fadd_rn(z4.z, dz);
            st.w = __fadd_rn(z4.w, dw);
            *(float4*)(orow + off) = st;
            s += (double)dx * dx + (double)dy * dy + (double)dz * dz + (double)dw * dw;
        }
        if (l == 0) outIdxF[row] = (float)kk;
    }
#pragma unroll
    for (int o = 32; o > 0; o >>= 1) s += __shfl_down(s, o, 64);
    if (l == 0) psum[w] = s;
    __syncthreads();
    if (tid == 0)
        atomicAdd(lossAcc, psum[0] + psum[1] + psum[2] + psum[3]);
}

__global__ void finalize_kernel(const double* __restrict__ lossAcc,
                                float* __restrict__ outLoss) {
    double m = *lossAcc / (double)((size_t)NROWS * DIM);
    float mf = (float)m;
    float c = __fmul_rn(0.25f, mf);
    *outLoss = __fadd_rn(c, mf);
}

// ---------------------------------------------------------------------------
// Fallback (ws too small): round-1 proven-correct VALU path, verbatim.
// ---------------------------------------------------------------------------
__device__ __forceinline__ float pairwise512_sq(const float* __restrict__ p) {
    float blk[4];
#pragma unroll
    for (int b = 0; b < 4; ++b) {
        const float* a = p + b * 128;
        float r[8];
#pragma unroll
        for (int j = 0; j < 8; ++j) r[j] = __fmul_rn(a[j], a[j]);
#pragma unroll
        for (int i = 8; i < 128; i += 8) {
#pragma unroll
            for (int j = 0; j < 8; ++j)
                r[j] = __fadd_rn(r[j], __fmul_rn(a[i + j], a[i + j]));
        }
        blk[b] = __fadd_rn(__fadd_rn(__fadd_rn(r[0], r[1]), __fadd_rn(r[2], r[3])),
                           __fadd_rn(__fadd_rn(r[4], r[5]), __fadd_rn(r[6], r[7])));
    }
    return __fadd_rn(__fadd_rn(blk[0], blk[1]), __fadd_rn(blk[2], blk[3]));
}

__global__ void ee_kernel(const float* __restrict__ E, float* __restrict__ ee) {
    int k = blockIdx.x * blockDim.x + threadIdx.x;
    if (k < KCB) ee[k] = pairwise512_sq(E + (size_t)k * DIM);
}

__global__ __launch_bounds__(512, 2)
void argmin_fallback(const float* __restrict__ Z, const float* __restrict__ E,
                     const float* __restrict__ ee, int* __restrict__ outIdx) {
    __shared__ __align__(16) char smem[(32 * 132 + 32 * 260) * 4];
    float (*As)[132] = (float (*)[132])smem;
    float (*Bs)[260] = (float (*)[260])(smem + 32 * 132 * 4);
    __shared__ float zzs[128];
    const int tid = threadIdx.x;
    const int tx = tid & 31;
    const int ty = tid >> 5;
    const int rowBase = blockIdx.x * 128;
    if (tid < 128) zzs[tid] = pairwise512_sq(Z + (size_t)(rowBase + tid) * DIM);
    __syncthreads();
    float zz[8];
#pragma unroll
    for (int m = 0; m < 8; ++m) zz[m] = zzs[ty * 8 + m];
    float bestV[8]; int bestI[8];
#pragma unroll
    for (int m = 0; m < 8; ++m) { bestV[m] = __builtin_inff(); bestI[m] = 0; }
    for (int tile = 0; tile < 32; ++tile) {
        float acc[8][8];
#pragma unroll
        for (int m = 0; m < 8; ++m)
#pragma unroll
            for (int n = 0; n < 8; ++n) acc[m][n] = 0.0f;
        for (int kc = 0; kc < DIM; kc += 32) {
            __syncthreads();
#pragma unroll
            for (int i = 0; i < 2; ++i) {
                int id4 = tid + i * 512;
                int r = id4 >> 3, c = id4 & 7;
                float4 v = *(const float4*)(Z + (size_t)(rowBase + r) * DIM + kc + c * 4);
                As[c * 4 + 0][r] = v.x; As[c * 4 + 1][r] = v.y;
                As[c * 4 + 2][r] = v.z; As[c * 4 + 3][r] = v.w;
            }
#pragma unroll
            for (int i = 0; i < 4; ++i) {
                int id4 = tid + i * 512;
                int r = id4 >> 3, c = id4 & 7;
                float4 v = *(const float4*)(E + (size_t)(tile * 256 + r) * DIM + kc + c * 4);
                Bs[c * 4 + 0][r] = v.x; Bs[c * 4 + 1][r] = v.y;
                Bs[c * 4 + 2][r] = v.z; Bs[c * 4 + 3][r] = v.w;
            }
            __syncthreads();
#pragma unroll
            for (int kk = 0; kk < 32; ++kk) {
                float a[8], b[8];
                *(float4*)&a[0] = *(const float4*)&As[kk][ty * 8];
                *(float4*)&a[4] = *(const float4*)&As[kk][ty * 8 + 4];
                *(float4*)&b[0] = *(const float4*)&Bs[kk][tx * 8];
                *(float4*)&b[4] = *(const float4*)&Bs[kk][tx * 8 + 4];
#pragma unroll
                for (int m = 0; m < 8; ++m)
#pragma unroll
                    for (int n = 0; n < 8; ++n)
                        acc[m][n] = __builtin_fmaf(a[m], b[n], acc[m][n]);
            }
        }
#pragma unroll
        for (int m = 0; m < 8; ++m) {
#pragma unroll
            for (int n = 0; n < 8; ++n) {
                float t = __builtin_fmaf(-2.0f, acc[m][n], zz[m]);
                float d2 = __fadd_rn(t, ee[tile * 256 + tx * 8 + n]);
                int kidx = tile * 256 + tx * 8 + n;
                if (d2 < bestV[m]) { bestV[m] = d2; bestI[m] = kidx; }
            }
        }
    }
    __syncthreads();
    float (*redV)[33] = (float (*)[33])smem;
    int   (*redI)[33] = (int (*)[33])(smem + 128 * 33 * 4);
#pragma unroll
    for (int m = 0; m < 8; ++m) {
        redV[ty * 8 + m][tx] = bestV[m];
        redI[ty * 8 + m][tx] = bestI[m];
    }
    __syncthreads();
    if (tid < 128) {
        float bv = redV[tid][0]; int bi = redI[tid][0];
        for (int j = 1; j < 32; ++j) {
            float v = redV[tid][j]; int ii = redI[tid][j];
            if (v < bv || (v == bv && ii < bi)) { bv = v; bi = ii; }
        }
        outIdx[rowBase + tid] = bi;
    }
}

__global__ void gather_kernel(const float* __restrict__ Z, const float* __restrict__ E,
                              const int* __restrict__ idx, float* __restrict__ outZ,
                              float* __restrict__ outIdxF, double* __restrict__ lossAcc) {
    int row = blockIdx.x;
    int t = threadIdx.x;  // 64
    int k = idx[row];
    const float* zr = Z + (size_t)row * DIM;
    const float* er = E + (size_t)k * DIM;
    float* orow = outZ + (size_t)row * DIM;
    double s = 0.0;
#pragma unroll
    for (int i = 0; i < 2; ++i) {
        int off = (t + i * 64) * 4;
        float4 z4 = *(const float4*)(zr + off);
        float4 e4 = *(const float4*)(er + off);
        float dx = __fsub_rn(e4.x, z4.x);
        float dy = __fsub_rn(e4.y, z4.y);
        float dz = __fsub_rn(e4.z, z4.z);
        float dw = __fsub_rn(e4.w, z4.w);
        float4 st;
        st.x = __fadd_rn(z4.x, dx);
        st.y = __fadd_rn(z4.y, dy);
        st.z = __fadd_rn(z4.z, dz);
        st.w = __fadd_rn(z4.w, dw);
        *(float4*)(orow + off) = st;
        s += (double)dx * dx + (double)dy * dy + (double)dz * dz + (double)dw * dw;
    }
#pragma unroll
    for (int o = 32; o > 0; o >>= 1) s += __shfl_down(s, o, 64);
    if (t == 0) {
        atomicAdd(lossAcc, s);
        outIdxF[row] = (float)k;
    }
}

// ---------------------------------------------------------------------------
extern "C" void kernel_launch(void* const* d_in, const int* in_sizes, int n_in,
                              void* d_out, int out_size, void* d_ws, size_t ws_size,
                              hipStream_t stream) {
    const float* Z = (const float*)d_in[0];
    const float* E = (const float*)d_in[1];
    float* out = (float*)d_out;
    float* zq_out = out;
    float* loss_out = out + (size_t)NROWS * DIM;
    float* idxf_out = loss_out + 1;

    if (ws_size >= WS_NEEDED) {
        _Float16* Zh = (_Float16*)((char*)d_ws + OFF_ZH);
        _Float16* Eh = (_Float16*)((char*)d_ws + OFF_EH);
        float* ee = (float*)((char*)d_ws + OFF_EE);
        float* zz = (float*)((char*)d_ws + OFF_ZZ);
        unsigned int* cnt = (unsigned int*)((char*)d_ws + OFF_CNT);
        unsigned int* cand = (unsigned int*)((char*)d_ws + OFF_CAND);
        double* lossAcc = (double*)((char*)d_ws + OFF_LOSS);

        prep_kernel<<<(NROWS + KCB) / 256, 256, 0, stream>>>(Z, E, Zh, Eh, zz, ee, cnt, lossAcc);
        screen_kernel<<<NROWS / 128, 512, 0, stream>>>(Zh, Eh, cnt, cand);
        finish_kernel<<<NROWS / 32, 256, 0, stream>>>(Z, E, zz, ee, cnt, cand,
                                                      zq_out, idxf_out, lossAcc);
        finalize_kernel<<<1, 1, 0, stream>>>(lossAcc, loss_out);
    } else {
        float* ee = (float*)d_ws;
        int* idx = (int*)((char*)d_ws + 32768);
        double* lossAcc = (double*)((char*)d_ws + 163840);
        hipMemsetAsync(lossAcc, 0, sizeof(double), stream);
        ee_kernel<<<KCB / 256, 256, 0, stream>>>(E, ee);
        argmin_fallback<<<NROWS / 128, 512, 0, stream>>>(Z, E, ee, idx);
        gather_kernel<<<NROWS, 64, 0, stream>>>(Z, E, idx, zq_out, idxf_out, lossAcc);
        finalize_kernel<<<1, 1, 0, stream>>>(lossAcc, loss_out);
    }
}